// Round 5
// baseline (124.869 us; speedup 1.0000x reference)
//
#include <hip/hip_runtime.h>

// Problem: B=4, H=16, S=2048, D=64
//   scores = Q K^T / 8 ; attn = tanh(0.3*scores) ; out = attn V   (mask unused)
// Round 5: R4 pipeline + (a) in-register P redistribution via
//   v_cvt_pk_bf16_f32 + v_permlane32/16_swap (kills the 8KB/wave-tile P LDS
//   round-trip), (b) Pade[5/4]+clamp tanh (1 trans op instead of 2).

constexpr int S_LEN = 2048;
constexpr int DIM   = 64;
constexpr int QT    = 256;
constexpr int KT    = 64;
constexpr int NKT   = S_LEN / KT;   // 32

typedef __bf16 bf16_t;
typedef bf16_t bf16x8 __attribute__((ext_vector_type(8)));
typedef float  f32x4  __attribute__((ext_vector_type(4)));

__device__ inline bf16x8 to_bf8(float4 a, float4 b) {
    bf16x8 v;
    v[0] = (bf16_t)a.x; v[1] = (bf16_t)a.y; v[2] = (bf16_t)a.z; v[3] = (bf16_t)a.w;
    v[4] = (bf16_t)b.x; v[5] = (bf16_t)b.y; v[6] = (bf16_t)b.z; v[7] = (bf16_t)b.w;
    return v;
}

// tanh(0.0375*s) via Pade[5/4] in y=0.0375*s, constants folded; clamped.
__device__ inline float tanh_pade(float s) {
    const float c1 = 7.41577148437e-08f;  // a^5
    const float c2 = 5.53710937500e-03f;  // 105 a^3
    const float c3 = 35.4375f;            // 945 a
    const float c4 = 2.96630859375e-05f;  // 15 a^4
    const float c5 = 0.590625f;           // 420 a^2
    float u = s * s;
    float n = __builtin_fmaf(u, __builtin_fmaf(u, c1, c2), c3);
    float d = __builtin_fmaf(u, __builtin_fmaf(u, c4, c5), 945.0f);
    float r = (s * n) * __builtin_amdgcn_rcpf(d);
    return fminf(1.0f, fmaxf(-1.0f, r));
}

__device__ inline void permlane32_swap(unsigned &a, unsigned &b) {
    asm("v_permlane32_swap_b32 %0, %1" : "+v"(a), "+v"(b));
}
__device__ inline void permlane16_swap(unsigned &a, unsigned &b) {
    asm("v_permlane16_swap_b32 %0, %1" : "+v"(a), "+v"(b));
}

__global__ __launch_bounds__(512, 4) void tanh_attn_kernel(
    const float* __restrict__ Q, const float* __restrict__ K,
    const float* __restrict__ V, float* __restrict__ O)
{
    const int tid  = threadIdx.x;
    const int lane = tid & 63;
    const int wv   = tid >> 6;          // wave id 0..7 (32 q-rows each)
    const int lr   = lane & 15;
    const int lg   = lane >> 4;

    // XCD-aware bijective swizzle (grid=512, 512%8==0)
    const int nwg = gridDim.x;
    const int bid = (blockIdx.x & 7) * (nwg >> 3) + (blockIdx.x >> 3);
    const int qtile = bid & 7;          // S/QT = 8
    const int bh    = bid >> 3;         // 0..63
    const int base  = bh * (S_LEN * DIM);
    const int q0    = qtile * QT;

    __shared__ bf16_t Ql[QT * DIM];     // 32 KB (Q staging only now)
    __shared__ bf16_t Kl[2][KT * DIM];  // 2 x 8 KB, [kv][d] swizzled
    __shared__ bf16_t Vt[2][DIM * KT];  // 2 x 8 KB, [d][kv] swizzled (V^T)

    const float* Kb = K + base;
    const float* Vb = V + base;

    // fixed per-thread staging map
    const int sr  = tid >> 3;           // K row 0..63
    const int sc8 = (tid & 7) * 8;      // K col chunk
    const int sd  = tid & 63;           // V d column
    const int skv = (tid >> 6) * 8;     // V kv chunk base

    // ---- issue tile-0 prefetch first (latency overlaps Q staging) ----
    float4 ka, kb2;
    float  vv[8];
    {
        const float* src = Kb + sr * DIM + sc8;
        ka  = *(const float4*)src;
        kb2 = *(const float4*)(src + 4);
        const float* vsrc = Vb + skv * DIM + sd;
        #pragma unroll
        for (int j = 0; j < 8; ++j) vv[j] = vsrc[j * DIM];
    }

    // ---- stage Q tile (f32 -> bf16, XOR swizzle (row&7)<<3) ----
    #pragma unroll
    for (int it = 0; it < 4; ++it) {
        int cid = tid + it * 512;           // 0..2047
        int r   = cid >> 3;
        int c8  = (cid & 7) * 8;
        const float* src = Q + base + (q0 + r) * DIM + c8;
        float4 a = *(const float4*)src;
        float4 b = *(const float4*)(src + 4);
        *(bf16x8*)&Ql[r * DIM + (c8 ^ ((r & 7) << 3))] = to_bf8(a, b);
    }
    __syncthreads();

    // ---- hoist Q fragments (wave's own 32 rows) ----
    bf16x8 qa[2][2];
    #pragma unroll
    for (int rt = 0; rt < 2; ++rt)
        #pragma unroll
        for (int ks = 0; ks < 2; ++ks) {
            int r = wv * 32 + rt * 16 + lr;
            int c = ks * 32 + lg * 8;
            qa[rt][ks] = *(const bf16x8*)&Ql[r * DIM + (c ^ ((r & 7) << 3))];
        }

    // ---- write tile 0 into buffer 0 ----
    {
        *(bf16x8*)&Kl[0][sr * DIM + (sc8 ^ ((sr & 7) << 3))] = to_bf8(ka, kb2);
        bf16x8 v;
        #pragma unroll
        for (int j = 0; j < 8; ++j) v[j] = (bf16_t)vv[j];
        *(bf16x8*)&Vt[0][sd * KT + (skv ^ ((sd & 7) << 3))] = v;
    }

    f32x4 oacc[2][4] = {};

    #pragma unroll 2
    for (int kt = 0; kt < NKT; ++kt) {
        const int cur = kt & 1;

        // ONE barrier per tile: publishes buf[cur] writes (end of kt-1) and
        // proves all waves finished reading buf[cur^1].
        __syncthreads();

        // next-tile global loads issued AFTER the barrier; land during compute
        if (kt + 1 < NKT) {
            const int k0n = (kt + 1) * KT;
            const float* src = Kb + (k0n + sr) * DIM + sc8;
            ka  = *(const float4*)src;
            kb2 = *(const float4*)(src + 4);
            const float* vsrc = Vb + (k0n + skv) * DIM + sd;
            #pragma unroll
            for (int j = 0; j < 8; ++j) vv[j] = vsrc[j * DIM];
        }

        const bf16_t* Kc = Kl[cur];
        const bf16_t* Vc = Vt[cur];

        // ---- GEMM1 (swapped): S^T = K · Q^T; D[m=kv][n=q] ----
        f32x4 sacc[2][4] = {};
        __builtin_amdgcn_s_setprio(1);
        #pragma unroll
        for (int ct = 0; ct < 4; ++ct) {
            int r = ct * 16 + lr;           // kv
            bf16x8 kf0 = *(const bf16x8*)&Kc[r * DIM + ((lg * 8)      ^ ((r & 7) << 3))];
            bf16x8 kf1 = *(const bf16x8*)&Kc[r * DIM + ((32 + lg * 8) ^ ((r & 7) << 3))];
            #pragma unroll
            for (int rt = 0; rt < 2; ++rt) {
                sacc[rt][ct] = __builtin_amdgcn_mfma_f32_16x16x32_bf16(kf0, qa[rt][0], sacc[rt][ct], 0, 0, 0);
                sacc[rt][ct] = __builtin_amdgcn_mfma_f32_16x16x32_bf16(kf1, qa[rt][1], sacc[rt][ct], 0, 0, 0);
            }
        }
        __builtin_amdgcn_s_setprio(0);

        // ---- tanh + in-register P redistribution (no LDS) ----
        // sacc layout: lane(lg,lr) holds S^T[kv=ct*16+lg*4+j][q=rt*16+lr].
        // Target A-frag pa[rt][ks]: lane holds P[q=rt*16+lr][k=ks*32+lg*8+e].
        // dword m of pa = (ct'=2ks+(lg>>1), lg'=2(lg&1)+(m>>1), jj'=m&1).
        // Realized per (ks,jj) pair via permlane32_swap then permlane16_swap.
        bf16x8 pa[2][2];
        #pragma unroll
        for (int rt = 0; rt < 2; ++rt) {
            unsigned dm[4][2];
            #pragma unroll
            for (int ct = 0; ct < 4; ++ct) {
                float p0 = tanh_pade(sacc[rt][ct][0]);
                float p1 = tanh_pade(sacc[rt][ct][1]);
                float p2 = tanh_pade(sacc[rt][ct][2]);
                float p3 = tanh_pade(sacc[rt][ct][3]);
                asm("v_cvt_pk_bf16_f32 %0, %1, %2" : "=v"(dm[ct][0]) : "v"(p0), "v"(p1));
                asm("v_cvt_pk_bf16_f32 %0, %1, %2" : "=v"(dm[ct][1]) : "v"(p2), "v"(p3));
            }
            #pragma unroll
            for (int ks = 0; ks < 2; ++ks) {
                union { unsigned u[4]; bf16x8 v; } pw;
                #pragma unroll
                for (int jj = 0; jj < 2; ++jj) {
                    unsigned A = dm[2 * ks][jj];
                    unsigned B = dm[2 * ks + 1][jj];
                    permlane32_swap(A, B);   // A=[A0,A1,B0,B1] B=[A2,A3,B2,B3]
                    permlane16_swap(A, B);   // A=[A0,A2,B0,B2] B=[A1,A3,B1,B3]
                    pw.u[jj]     = A;        // dwords m=0,1
                    pw.u[2 + jj] = B;        // dwords m=2,3
                }
                pa[rt][ks] = pw.v;
            }
        }

        // ---- GEMM2: O += P · V ----
        __builtin_amdgcn_s_setprio(1);
        #pragma unroll
        for (int dt = 0; dt < 4; ++dt) {
            int d = dt * 16 + lr;
            bf16x8 vf0 = *(const bf16x8*)&Vc[d * KT + ((lg * 8)      ^ ((d & 7) << 3))];
            bf16x8 vf1 = *(const bf16x8*)&Vc[d * KT + ((32 + lg * 8) ^ ((d & 7) << 3))];
            #pragma unroll
            for (int rt = 0; rt < 2; ++rt) {
                oacc[rt][dt] = __builtin_amdgcn_mfma_f32_16x16x32_bf16(pa[rt][0], vf0, oacc[rt][dt], 0, 0, 0);
                oacc[rt][dt] = __builtin_amdgcn_mfma_f32_16x16x32_bf16(pa[rt][1], vf1, oacc[rt][dt], 0, 0, 0);
            }
        }
        __builtin_amdgcn_s_setprio(0);

        // ---- write next tile into the other buffer ----
        if (kt + 1 < NKT) {
            const int nxt = cur ^ 1;
            *(bf16x8*)&Kl[nxt][sr * DIM + (sc8 ^ ((sr & 7) << 3))] = to_bf8(ka, kb2);
            bf16x8 v;
            #pragma unroll
            for (int j = 0; j < 8; ++j) v[j] = (bf16_t)vv[j];
            *(bf16x8*)&Vt[nxt][sd * KT + (skv ^ ((sd & 7) << 3))] = v;
        }
    }

    // ---- epilogue: write O (f32) ----
    #pragma unroll
    for (int rt = 0; rt < 2; ++rt)
        #pragma unroll
        for (int dt = 0; dt < 4; ++dt)
            #pragma unroll
            for (int j = 0; j < 4; ++j) {
                int q = q0 + wv * 32 + rt * 16 + lg * 4 + j;
                int d = dt * 16 + lr;
                O[base + q * DIM + d] = oacc[rt][dt][j];
            }
}

extern "C" void kernel_launch(void* const* d_in, const int* in_sizes, int n_in,
                              void* d_out, int out_size, void* d_ws, size_t ws_size,
                              hipStream_t stream) {
    const float* Q = (const float*)d_in[0];
    const float* K = (const float*)d_in[1];
    const float* V = (const float*)d_in[2];
    float* O = (float*)d_out;
    dim3 grid(64 * (S_LEN / QT));   // 512 blocks
    dim3 block(512);
    hipLaunchKernelGGL(tanh_attn_kernel, grid, block, 0, stream, Q, K, V, O);
}

// Round 6
// 113.664 us; speedup vs baseline: 1.0986x; 1.0986x over previous
//
#include <hip/hip_runtime.h>

// Problem: B=4, H=16, S=2048, D=64
//   scores = Q K^T / 8 ; attn = tanh(0.3*scores) ; out = attn V   (mask unused)
// Round 6: R4 pipeline + in-register P (no LDS round-trip), implemented
//   per m240 lesson: compiler-generated cvt_pk (plain casts), asm only for
//   the two permlane swaps. Per-rt conversion to cap register pressure.

constexpr int S_LEN = 2048;
constexpr int DIM   = 64;
constexpr int QT    = 256;
constexpr int KT    = 64;
constexpr int NKT   = S_LEN / KT;   // 32

// tanh(a*x) = 1 - 2/(exp2(2*a*x*log2e)+1); a = 0.3/8 = 0.0375
constexpr float C_EXP2 = 0.10820212528f;

typedef __bf16 bf16_t;
typedef bf16_t bf16x8 __attribute__((ext_vector_type(8)));
typedef float  f32x4  __attribute__((ext_vector_type(4)));

__device__ inline bf16x8 to_bf8(float4 a, float4 b) {
    bf16x8 v;
    v[0] = (bf16_t)a.x; v[1] = (bf16_t)a.y; v[2] = (bf16_t)a.z; v[3] = (bf16_t)a.w;
    v[4] = (bf16_t)b.x; v[5] = (bf16_t)b.y; v[6] = (bf16_t)b.z; v[7] = (bf16_t)b.w;
    return v;
}

__device__ inline float tanh_fast(float s) {
    float t = __builtin_amdgcn_exp2f(s * C_EXP2);
    return 1.0f - 2.0f * __builtin_amdgcn_rcpf(t + 1.0f);
}

// plain casts -> compiler emits v_cvt_pk_bf16_f32 and schedules freely
__device__ inline unsigned pack2_bf16(float p0, float p1) {
    union { bf16_t h[2]; unsigned u; } pk;
    pk.h[0] = (bf16_t)p0; pk.h[1] = (bf16_t)p1;
    return pk.u;
}

__device__ inline void permlane32_swap(unsigned &a, unsigned &b) {
    asm("v_permlane32_swap_b32 %0, %1" : "+v"(a), "+v"(b));
}
__device__ inline void permlane16_swap(unsigned &a, unsigned &b) {
    asm("v_permlane16_swap_b32 %0, %1" : "+v"(a), "+v"(b));
}

__global__ __launch_bounds__(512, 4) void tanh_attn_kernel(
    const float* __restrict__ Q, const float* __restrict__ K,
    const float* __restrict__ V, float* __restrict__ O)
{
    const int tid  = threadIdx.x;
    const int lane = tid & 63;
    const int wv   = tid >> 6;          // wave id 0..7 (32 q-rows each)
    const int lr   = lane & 15;
    const int lg   = lane >> 4;

    // XCD-aware bijective swizzle (grid=512, 512%8==0)
    const int nwg = gridDim.x;
    const int bid = (blockIdx.x & 7) * (nwg >> 3) + (blockIdx.x >> 3);
    const int qtile = bid & 7;          // S/QT = 8
    const int bh    = bid >> 3;         // 0..63
    const int base  = bh * (S_LEN * DIM);
    const int q0    = qtile * QT;

    __shared__ bf16_t Ql[QT * DIM];     // 32 KB (Q staging only)
    __shared__ bf16_t Kl[2][KT * DIM];  // 2 x 8 KB, [kv][d] swizzled
    __shared__ bf16_t Vt[2][DIM * KT];  // 2 x 8 KB, [d][kv] swizzled (V^T)

    const float* Kb = K + base;
    const float* Vb = V + base;

    // fixed per-thread staging map
    const int sr  = tid >> 3;           // K row 0..63
    const int sc8 = (tid & 7) * 8;      // K col chunk
    const int sd  = tid & 63;           // V d column
    const int skv = (tid >> 6) * 8;     // V kv chunk base

    // ---- issue tile-0 prefetch first (latency overlaps Q staging) ----
    float4 ka, kb2;
    float  vv[8];
    {
        const float* src = Kb + sr * DIM + sc8;
        ka  = *(const float4*)src;
        kb2 = *(const float4*)(src + 4);
        const float* vsrc = Vb + skv * DIM + sd;
        #pragma unroll
        for (int j = 0; j < 8; ++j) vv[j] = vsrc[j * DIM];
    }

    // ---- stage Q tile (f32 -> bf16, XOR swizzle (row&7)<<3) ----
    #pragma unroll
    for (int it = 0; it < 4; ++it) {
        int cid = tid + it * 512;           // 0..2047
        int r   = cid >> 3;
        int c8  = (cid & 7) * 8;
        const float* src = Q + base + (q0 + r) * DIM + c8;
        float4 a = *(const float4*)src;
        float4 b = *(const float4*)(src + 4);
        *(bf16x8*)&Ql[r * DIM + (c8 ^ ((r & 7) << 3))] = to_bf8(a, b);
    }
    __syncthreads();

    // ---- hoist Q fragments (wave's own 32 rows) ----
    bf16x8 qa[2][2];
    #pragma unroll
    for (int rt = 0; rt < 2; ++rt)
        #pragma unroll
        for (int ks = 0; ks < 2; ++ks) {
            int r = wv * 32 + rt * 16 + lr;
            int c = ks * 32 + lg * 8;
            qa[rt][ks] = *(const bf16x8*)&Ql[r * DIM + (c ^ ((r & 7) << 3))];
        }

    // ---- write tile 0 into buffer 0 ----
    {
        *(bf16x8*)&Kl[0][sr * DIM + (sc8 ^ ((sr & 7) << 3))] = to_bf8(ka, kb2);
        bf16x8 v;
        #pragma unroll
        for (int j = 0; j < 8; ++j) v[j] = (bf16_t)vv[j];
        *(bf16x8*)&Vt[0][sd * KT + (skv ^ ((sd & 7) << 3))] = v;
    }

    f32x4 oacc[2][4] = {};

    #pragma unroll 2
    for (int kt = 0; kt < NKT; ++kt) {
        const int cur = kt & 1;

        // ONE barrier per tile: publishes buf[cur] writes (end of kt-1) and
        // proves all waves finished reading buf[cur^1].
        __syncthreads();

        // next-tile global loads issued AFTER the barrier; land during compute
        if (kt + 1 < NKT) {
            const int k0n = (kt + 1) * KT;
            const float* src = Kb + (k0n + sr) * DIM + sc8;
            ka  = *(const float4*)src;
            kb2 = *(const float4*)(src + 4);
            const float* vsrc = Vb + (k0n + skv) * DIM + sd;
            #pragma unroll
            for (int j = 0; j < 8; ++j) vv[j] = vsrc[j * DIM];
        }

        const bf16_t* Kc = Kl[cur];
        const bf16_t* Vc = Vt[cur];

        // ---- GEMM1 (swapped): S^T = K · Q^T; D[m=kv][n=q] ----
        f32x4 sacc[2][4] = {};
        __builtin_amdgcn_s_setprio(1);
        #pragma unroll
        for (int ct = 0; ct < 4; ++ct) {
            int r = ct * 16 + lr;           // kv
            bf16x8 kf0 = *(const bf16x8*)&Kc[r * DIM + ((lg * 8)      ^ ((r & 7) << 3))];
            bf16x8 kf1 = *(const bf16x8*)&Kc[r * DIM + ((32 + lg * 8) ^ ((r & 7) << 3))];
            #pragma unroll
            for (int rt = 0; rt < 2; ++rt) {
                sacc[rt][ct] = __builtin_amdgcn_mfma_f32_16x16x32_bf16(kf0, qa[rt][0], sacc[rt][ct], 0, 0, 0);
                sacc[rt][ct] = __builtin_amdgcn_mfma_f32_16x16x32_bf16(kf1, qa[rt][1], sacc[rt][ct], 0, 0, 0);
            }
        }
        __builtin_amdgcn_s_setprio(0);

        // ---- tanh + in-register P redistribution (no LDS) ----
        // sacc: lane(lg,lr) holds S^T[kv=ct*16+lg*4+j][q=rt*16+lr].
        // pa[rt][ks] A-frag: lane holds P[q=rt*16+lr][kv=ks*32+lg*8+e], e=0..7.
        // dword m of pa <- dm[ct=2ks+(lg>>1)][jj=m&1] from lane-group
        // 2(lg&1)+(m>>1); realized by permlane32_swap then permlane16_swap:
        //   (A,B)=(dm[2ks][jj],dm[2ks+1][jj]) -> A=[A0,A2,B0,B2] B=[A1,A3,B1,B3]
        // Converted per-rt so sacc[rt] dies before the next rt (reg pressure).
        bf16x8 pa[2][2];
        #pragma unroll
        for (int rt = 0; rt < 2; ++rt) {
            unsigned dm[4][2];
            #pragma unroll
            for (int ct = 0; ct < 4; ++ct) {
                dm[ct][0] = pack2_bf16(tanh_fast(sacc[rt][ct][0]),
                                       tanh_fast(sacc[rt][ct][1]));
                dm[ct][1] = pack2_bf16(tanh_fast(sacc[rt][ct][2]),
                                       tanh_fast(sacc[rt][ct][3]));
            }
            #pragma unroll
            for (int ks = 0; ks < 2; ++ks) {
                union { unsigned u[4]; bf16x8 v; } pw;
                #pragma unroll
                for (int jj = 0; jj < 2; ++jj) {
                    unsigned A = dm[2 * ks][jj];
                    unsigned B = dm[2 * ks + 1][jj];
                    permlane32_swap(A, B);
                    permlane16_swap(A, B);
                    pw.u[jj]     = A;
                    pw.u[2 + jj] = B;
                }
                pa[rt][ks] = pw.v;
            }
        }

        // ---- write next tile into the other buffer (loads have landed by
        //      now; doing it here frees the staging regs before GEMM2 and
        //      gives the ds_writes slack before the next barrier) ----
        if (kt + 1 < NKT) {
            const int nxt = cur ^ 1;
            *(bf16x8*)&Kl[nxt][sr * DIM + (sc8 ^ ((sr & 7) << 3))] = to_bf8(ka, kb2);
            bf16x8 v;
            #pragma unroll
            for (int j = 0; j < 8; ++j) v[j] = (bf16_t)vv[j];
            *(bf16x8*)&Vt[nxt][sd * KT + (skv ^ ((sd & 7) << 3))] = v;
        }

        // ---- GEMM2: O += P · V ----
        __builtin_amdgcn_s_setprio(1);
        #pragma unroll
        for (int dt = 0; dt < 4; ++dt) {
            int d = dt * 16 + lr;
            bf16x8 vf0 = *(const bf16x8*)&Vc[d * KT + ((lg * 8)      ^ ((d & 7) << 3))];
            bf16x8 vf1 = *(const bf16x8*)&Vc[d * KT + ((32 + lg * 8) ^ ((d & 7) << 3))];
            #pragma unroll
            for (int rt = 0; rt < 2; ++rt) {
                oacc[rt][dt] = __builtin_amdgcn_mfma_f32_16x16x32_bf16(pa[rt][0], vf0, oacc[rt][dt], 0, 0, 0);
                oacc[rt][dt] = __builtin_amdgcn_mfma_f32_16x16x32_bf16(pa[rt][1], vf1, oacc[rt][dt], 0, 0, 0);
            }
        }
        __builtin_amdgcn_s_setprio(0);
    }

    // ---- epilogue: write O (f32) ----
    #pragma unroll
    for (int rt = 0; rt < 2; ++rt)
        #pragma unroll
        for (int dt = 0; dt < 4; ++dt)
            #pragma unroll
            for (int j = 0; j < 4; ++j) {
                int q = q0 + wv * 32 + rt * 16 + lg * 4 + j;
                int d = dt * 16 + lr;
                O[base + q * DIM + d] = oacc[rt][dt][j];
            }
}

extern "C" void kernel_launch(void* const* d_in, const int* in_sizes, int n_in,
                              void* d_out, int out_size, void* d_ws, size_t ws_size,
                              hipStream_t stream) {
    const float* Q = (const float*)d_in[0];
    const float* K = (const float*)d_in[1];
    const float* V = (const float*)d_in[2];
    float* O = (float*)d_out;
    dim3 grid(64 * (S_LEN / QT));   // 512 blocks
    dim3 block(512);
    hipLaunchKernelGGL(tanh_attn_kernel, grid, block, 0, stream, Q, K, V, O);
}

// Round 7
// 113.154 us; speedup vs baseline: 1.1035x; 1.0045x over previous
//
#include <hip/hip_runtime.h>

// Problem: B=4, H=16, S=2048, D=64
//   scores = Q K^T / 8 ; attn = tanh(0.3*scores) ; out = attn V   (mask unused)
// Round 7: R6 + phase interleave. Evidence (R3/R6): LDS has slack; wall ≈
//   sum of serialized phases (GEMM1 | tanh | GEMM2). Split GEMM2 by k-half
//   and interleave tanh/staging into MFMA shadows:
//   GEMM1 -> tanh(ct01)->pa0 -> GEMM2-ks0 -> tanh(ct23)->pa1 -> stage-writes
//   -> GEMM2-ks1.

constexpr int S_LEN = 2048;
constexpr int DIM   = 64;
constexpr int QT    = 256;
constexpr int KT    = 64;
constexpr int NKT   = S_LEN / KT;   // 32

// tanh(a*x) = 1 - 2/(exp2(2*a*x*log2e)+1); a = 0.3/8 = 0.0375
constexpr float C_EXP2 = 0.10820212528f;

typedef __bf16 bf16_t;
typedef bf16_t bf16x8 __attribute__((ext_vector_type(8)));
typedef float  f32x4  __attribute__((ext_vector_type(4)));

__device__ inline bf16x8 to_bf8(float4 a, float4 b) {
    bf16x8 v;
    v[0] = (bf16_t)a.x; v[1] = (bf16_t)a.y; v[2] = (bf16_t)a.z; v[3] = (bf16_t)a.w;
    v[4] = (bf16_t)b.x; v[5] = (bf16_t)b.y; v[6] = (bf16_t)b.z; v[7] = (bf16_t)b.w;
    return v;
}

__device__ inline float tanh_fast(float s) {
    float t = __builtin_amdgcn_exp2f(s * C_EXP2);
    return 1.0f - 2.0f * __builtin_amdgcn_rcpf(t + 1.0f);
}

// plain casts -> compiler emits v_cvt_pk_bf16_f32 and schedules freely
__device__ inline unsigned pack2_bf16(float p0, float p1) {
    union { bf16_t h[2]; unsigned u; } pk;
    pk.h[0] = (bf16_t)p0; pk.h[1] = (bf16_t)p1;
    return pk.u;
}

__device__ inline void permlane32_swap(unsigned &a, unsigned &b) {
    asm("v_permlane32_swap_b32 %0, %1" : "+v"(a), "+v"(b));
}
__device__ inline void permlane16_swap(unsigned &a, unsigned &b) {
    asm("v_permlane16_swap_b32 %0, %1" : "+v"(a), "+v"(b));
}

__global__ __launch_bounds__(512, 4) void tanh_attn_kernel(
    const float* __restrict__ Q, const float* __restrict__ K,
    const float* __restrict__ V, float* __restrict__ O)
{
    const int tid  = threadIdx.x;
    const int lane = tid & 63;
    const int wv   = tid >> 6;          // wave id 0..7 (32 q-rows each)
    const int lr   = lane & 15;
    const int lg   = lane >> 4;

    // XCD-aware bijective swizzle (grid=512, 512%8==0)
    const int nwg = gridDim.x;
    const int bid = (blockIdx.x & 7) * (nwg >> 3) + (blockIdx.x >> 3);
    const int qtile = bid & 7;          // S/QT = 8
    const int bh    = bid >> 3;         // 0..63
    const int base  = bh * (S_LEN * DIM);
    const int q0    = qtile * QT;

    __shared__ bf16_t Ql[QT * DIM];     // 32 KB (Q staging only)
    __shared__ bf16_t Kl[2][KT * DIM];  // 2 x 8 KB, [kv][d] swizzled
    __shared__ bf16_t Vt[2][DIM * KT];  // 2 x 8 KB, [d][kv] swizzled (V^T)

    const float* Kb = K + base;
    const float* Vb = V + base;

    // fixed per-thread staging map
    const int sr  = tid >> 3;           // K row 0..63
    const int sc8 = (tid & 7) * 8;      // K col chunk
    const int sd  = tid & 63;           // V d column
    const int skv = (tid >> 6) * 8;     // V kv chunk base

    // ---- issue tile-0 prefetch first (latency overlaps Q staging) ----
    float4 ka, kb2;
    float  vv[8];
    {
        const float* src = Kb + sr * DIM + sc8;
        ka  = *(const float4*)src;
        kb2 = *(const float4*)(src + 4);
        const float* vsrc = Vb + skv * DIM + sd;
        #pragma unroll
        for (int j = 0; j < 8; ++j) vv[j] = vsrc[j * DIM];
    }

    // ---- stage Q tile (f32 -> bf16, XOR swizzle (row&7)<<3) ----
    #pragma unroll
    for (int it = 0; it < 4; ++it) {
        int cid = tid + it * 512;           // 0..2047
        int r   = cid >> 3;
        int c8  = (cid & 7) * 8;
        const float* src = Q + base + (q0 + r) * DIM + c8;
        float4 a = *(const float4*)src;
        float4 b = *(const float4*)(src + 4);
        *(bf16x8*)&Ql[r * DIM + (c8 ^ ((r & 7) << 3))] = to_bf8(a, b);
    }
    __syncthreads();

    // ---- hoist Q fragments (wave's own 32 rows) ----
    bf16x8 qa[2][2];
    #pragma unroll
    for (int rt = 0; rt < 2; ++rt)
        #pragma unroll
        for (int ks = 0; ks < 2; ++ks) {
            int r = wv * 32 + rt * 16 + lr;
            int c = ks * 32 + lg * 8;
            qa[rt][ks] = *(const bf16x8*)&Ql[r * DIM + (c ^ ((r & 7) << 3))];
        }

    // ---- write tile 0 into buffer 0 ----
    {
        *(bf16x8*)&Kl[0][sr * DIM + (sc8 ^ ((sr & 7) << 3))] = to_bf8(ka, kb2);
        bf16x8 v;
        #pragma unroll
        for (int j = 0; j < 8; ++j) v[j] = (bf16_t)vv[j];
        *(bf16x8*)&Vt[0][sd * KT + (skv ^ ((sd & 7) << 3))] = v;
    }

    f32x4 oacc[2][4] = {};

    #pragma unroll 2
    for (int kt = 0; kt < NKT; ++kt) {
        const int cur = kt & 1;

        // ONE barrier per tile: publishes buf[cur] writes (end of kt-1) and
        // proves all waves finished reading buf[cur^1].
        __syncthreads();

        // next-tile global loads issued AFTER the barrier; land during compute
        if (kt + 1 < NKT) {
            const int k0n = (kt + 1) * KT;
            const float* src = Kb + (k0n + sr) * DIM + sc8;
            ka  = *(const float4*)src;
            kb2 = *(const float4*)(src + 4);
            const float* vsrc = Vb + (k0n + skv) * DIM + sd;
            #pragma unroll
            for (int j = 0; j < 8; ++j) vv[j] = vsrc[j * DIM];
        }

        const bf16_t* Kc = Kl[cur];
        const bf16_t* Vc = Vt[cur];

        // ---- GEMM1 (swapped): S^T = K · Q^T; D[m=kv][n=q] ----
        f32x4 sacc[2][4] = {};
        __builtin_amdgcn_s_setprio(1);
        #pragma unroll
        for (int ct = 0; ct < 4; ++ct) {
            int r = ct * 16 + lr;           // kv
            bf16x8 kf0 = *(const bf16x8*)&Kc[r * DIM + ((lg * 8)      ^ ((r & 7) << 3))];
            bf16x8 kf1 = *(const bf16x8*)&Kc[r * DIM + ((32 + lg * 8) ^ ((r & 7) << 3))];
            #pragma unroll
            for (int rt = 0; rt < 2; ++rt) {
                sacc[rt][ct] = __builtin_amdgcn_mfma_f32_16x16x32_bf16(kf0, qa[rt][0], sacc[rt][ct], 0, 0, 0);
                sacc[rt][ct] = __builtin_amdgcn_mfma_f32_16x16x32_bf16(kf1, qa[rt][1], sacc[rt][ct], 0, 0, 0);
            }
        }
        __builtin_amdgcn_s_setprio(0);

        // sacc: lane(lg,lr) holds S^T[kv=ct*16+lg*4+j][q=rt*16+lr].
        // pa[rt][ks] A-frag: lane holds P[q=rt*16+lr][kv=ks*32+lg*8+e], e=0..7.
        // Built from dm[ct=2ks+(lg>>1)][jj] via permlane32_swap + permlane16_swap.
        bf16x8 pa[2][2];

        // ---- tanh + redistribute for ks=0 (ct=0,1) ----
        #pragma unroll
        for (int rt = 0; rt < 2; ++rt) {
            unsigned dm[2][2];
            #pragma unroll
            for (int c = 0; c < 2; ++c) {
                dm[c][0] = pack2_bf16(tanh_fast(sacc[rt][c][0]),
                                      tanh_fast(sacc[rt][c][1]));
                dm[c][1] = pack2_bf16(tanh_fast(sacc[rt][c][2]),
                                      tanh_fast(sacc[rt][c][3]));
            }
            union { unsigned u[4]; bf16x8 v; } pw;
            #pragma unroll
            for (int jj = 0; jj < 2; ++jj) {
                unsigned A = dm[0][jj];
                unsigned B = dm[1][jj];
                permlane32_swap(A, B);
                permlane16_swap(A, B);
                pw.u[jj]     = A;
                pw.u[2 + jj] = B;
            }
            pa[rt][0] = pw.v;
        }

        // ---- GEMM2 ks=0: O += P[:, 0:32] · V[0:32, :]  (8 mfma) ----
        // tanh(ct2,3) below issues into these MFMAs' pipe shadows.
        __builtin_amdgcn_s_setprio(1);
        #pragma unroll
        for (int dt = 0; dt < 4; ++dt) {
            int d = dt * 16 + lr;
            bf16x8 vf0 = *(const bf16x8*)&Vc[d * KT + ((lg * 8) ^ ((d & 7) << 3))];
            #pragma unroll
            for (int rt = 0; rt < 2; ++rt)
                oacc[rt][dt] = __builtin_amdgcn_mfma_f32_16x16x32_bf16(pa[rt][0], vf0, oacc[rt][dt], 0, 0, 0);
        }
        __builtin_amdgcn_s_setprio(0);

        // ---- tanh + redistribute for ks=1 (ct=2,3) ----
        #pragma unroll
        for (int rt = 0; rt < 2; ++rt) {
            unsigned dm[2][2];
            #pragma unroll
            for (int c = 0; c < 2; ++c) {
                dm[c][0] = pack2_bf16(tanh_fast(sacc[rt][2 + c][0]),
                                      tanh_fast(sacc[rt][2 + c][1]));
                dm[c][1] = pack2_bf16(tanh_fast(sacc[rt][2 + c][2]),
                                      tanh_fast(sacc[rt][2 + c][3]));
            }
            union { unsigned u[4]; bf16x8 v; } pw;
            #pragma unroll
            for (int jj = 0; jj < 2; ++jj) {
                unsigned A = dm[0][jj];
                unsigned B = dm[1][jj];
                permlane32_swap(A, B);
                permlane16_swap(A, B);
                pw.u[jj]     = A;
                pw.u[2 + jj] = B;
            }
            pa[rt][1] = pw.v;
        }

        // ---- staging writes for kt+1 (loads long landed; overlaps GEMM2) ----
        if (kt + 1 < NKT) {
            const int nxt = cur ^ 1;
            *(bf16x8*)&Kl[nxt][sr * DIM + (sc8 ^ ((sr & 7) << 3))] = to_bf8(ka, kb2);
            bf16x8 v;
            #pragma unroll
            for (int j = 0; j < 8; ++j) v[j] = (bf16_t)vv[j];
            *(bf16x8*)&Vt[nxt][sd * KT + (skv ^ ((sd & 7) << 3))] = v;
        }

        // ---- GEMM2 ks=1: O += P[:, 32:64] · V[32:64, :]  (8 mfma) ----
        __builtin_amdgcn_s_setprio(1);
        #pragma unroll
        for (int dt = 0; dt < 4; ++dt) {
            int d = dt * 16 + lr;
            bf16x8 vf1 = *(const bf16x8*)&Vc[d * KT + ((32 + lg * 8) ^ ((d & 7) << 3))];
            #pragma unroll
            for (int rt = 0; rt < 2; ++rt)
                oacc[rt][dt] = __builtin_amdgcn_mfma_f32_16x16x32_bf16(pa[rt][1], vf1, oacc[rt][dt], 0, 0, 0);
        }
        __builtin_amdgcn_s_setprio(0);
    }

    // ---- epilogue: write O (f32) ----
    #pragma unroll
    for (int rt = 0; rt < 2; ++rt)
        #pragma unroll
        for (int dt = 0; dt < 4; ++dt)
            #pragma unroll
            for (int j = 0; j < 4; ++j) {
                int q = q0 + wv * 32 + rt * 16 + lg * 4 + j;
                int d = dt * 16 + lr;
                O[base + q * DIM + d] = oacc[rt][dt][j];
            }
}

extern "C" void kernel_launch(void* const* d_in, const int* in_sizes, int n_in,
                              void* d_out, int out_size, void* d_ws, size_t ws_size,
                              hipStream_t stream) {
    const float* Q = (const float*)d_in[0];
    const float* K = (const float*)d_in[1];
    const float* V = (const float*)d_in[2];
    float* O = (float*)d_out;
    dim3 grid(64 * (S_LEN / QT));   // 512 blocks
    dim3 block(512);
    hipLaunchKernelGGL(tanh_attn_kernel, grid, block, 0, stream, Q, K, V, O);
}